// Round 11
// baseline (255.162 us; speedup 1.0000x reference)
//
#include <hip/hip_runtime.h>
#include <stdint.h>

// ---- problem constants ----
#define HEADS 8
#define KSZ   4
#define STRD  2
#define BB    8
#define LL    2048
#define CC    1024
#define N3    3072
#define NW    1023            // windows
#define M1    (BB*LL)         // 16384 rows of qkv GEMM (and of z GEMM)
#define GK    1024            // K of both GEMMs
#define NTT   16              // K-tiles per output tile (GK/64)

typedef __bf16 bf16;
typedef __bf16 bf16x8 __attribute__((ext_vector_type(8)));
typedef float  f32x16 __attribute__((ext_vector_type(16)));
typedef unsigned int  u32;
typedef unsigned short u16;

__device__ __forceinline__ float bflo(u32 u) { return __uint_as_float(u << 16); }
__device__ __forceinline__ float bfhi(u32 u) { return __uint_as_float(u & 0xffff0000u); }
__device__ __forceinline__ u16 f2bf(float f) { bf16 b = (bf16)f; return __builtin_bit_cast(u16, b); }

#define AS3(p) ((__attribute__((address_space(3))) void*)(p))
#define AS1(p) ((const __attribute__((address_space(1))) void*)(p))

// ---------------- cast x (f32 -> bf16), vectorized ----------------
__global__ __launch_bounds__(256) void cast_x_k(const float* __restrict__ in,
                                                bf16* __restrict__ out, int n4)
{
    int i = blockIdx.x * 256 + threadIdx.x;
    int stride = gridDim.x * 256;
    for (; i < n4; i += stride) {
        float4 f = reinterpret_cast<const float4*>(in)[i];
        ushort4 u;
        u.x = f2bf(f.x); u.y = f2bf(f.y); u.z = f2bf(f.z); u.w = f2bf(f.w);
        reinterpret_cast<ushort4*>(out)[i] = u;
    }
}

// ---------------- transpose + cast: src f32 [R][Ccol] -> dst bf16 [Ccol][R] ----------------
__global__ __launch_bounds__(256) void transpose_cast_k(const float* __restrict__ src,
                                                        bf16* __restrict__ dst,
                                                        int R, int Ccol)
{
    __shared__ float t[32][33];
    int tx = threadIdx.x & 31, ty = threadIdx.x >> 5;   // 32 x 8
    int c0 = blockIdx.x * 32, r0 = blockIdx.y * 32;
#pragma unroll
    for (int yy = 0; yy < 32; yy += 8)
        t[ty + yy][tx] = src[(size_t)(r0 + ty + yy) * Ccol + c0 + tx];
    __syncthreads();
#pragma unroll
    for (int yy = 0; yy < 32; yy += 8)
        dst[(size_t)(c0 + ty + yy) * R + r0 + tx] = (bf16)t[tx][ty + yy];
}

// ---------------- persistent 256x256 bf16 GEMM: r8 schedule, 32x32x16 MFMA ----------------
// Schedule/ledger = round-8 verified body (rolled j-loop, reads after leading
// barrier, stage A(j+2)@P3, B(j+2)@P4 into buf[j&1], vmcnt(8)@P4, vmcnt(0)@JT-2).
// ONLY change: MFMA shape 16x16x32 -> 32x32x16 (+15% ceiling, half the instrs).
// A-frag: lane l holds row=l&31, k=(l>>5)*8..+7 (byte off ks*32+(l>>5)*16 ^ xr).
// C/D: col=l&31, row=(reg&3)+8*(reg>>2)+4*(l>>5)  [m74/m101-verified layout].
__device__ __forceinline__ void stage8(const bf16* __restrict__ G, bf16* dst,
                                       int baserow, int kt,
                                       int wid, int l, int kch)
{
#pragma unroll
    for (int qd = 0; qd < 4; ++qd) {
        int row = ((wid * 4 + qd) << 3) + (l >> 3);
        const bf16* src = G + (size_t)(baserow + row) * GK + kt * 64 + kch;
        __builtin_amdgcn_global_load_lds(AS1(src), AS3(dst + (wid * 4 + qd) * 512), 16, 0, 0);
    }
}

template <int OUT_MODE, int T, int NBN>
__global__ __launch_bounds__(512, 1) void gemm8p_k(const bf16* __restrict__ A,
                                                   const bf16* __restrict__ Bt,
                                                   void* __restrict__ Cout,
                                                   const float* __restrict__ bias)
{
    __shared__ __attribute__((aligned(16))) bf16 sA[2][256 * 64];
    __shared__ __attribute__((aligned(16))) bf16 sB[2][256 * 64];
    const int Nn = NBN << 8;

    const int tid = threadIdx.x;
    const int l = tid & 63, wid = tid >> 6;
    const int wm = wid >> 2, wn = wid & 3;
    const int l31 = l & 31, l5 = l >> 5;
    const int xr = (l & 7) << 4;                      // read-side byte XOR (row&7 == l&7)
    const int kch = ((l & 7) ^ ((l >> 3) & 7)) * 8;   // write-side inverse-swizzled k offset

    // XCD-aware block swizzle (grid = 256, % 8 == 0, bijective)
    const int nwg = gridDim.x;
    const int wg = ((blockIdx.x & 7) * (nwg >> 3)) + (blockIdx.x >> 3);
    const int JT = T * NTT;

    int ti = wg * T;                                  // current output tile
    int m0 = (ti / NBN) << 8, n0 = (ti % NBN) << 8;

    const int rA = wm * 128 + l31;                    // A frag row base in tile
    const int rB = wn * 64 + l31;                     // B frag row base in tile
    int offK[4];                                      // per-ks swizzled bf16 offset in row
#pragma unroll
    for (int ks = 0; ks < 4; ++ks)
        offK[ks] = ((ks * 32 + l5 * 16) ^ xr) >> 1;

    f32x16 acc[4][2] = {};
    bf16x8 aLo[2][4], aHi[2][4], bLo[4], bHi[4];

    // prologue: K-tile 0 -> buf0, K-tile 1 -> buf1 (tile ti)
    stage8(A, sA[0], m0, 0, wid, l, kch);
    stage8(Bt, sB[0], n0, 0, wid, l, kch);
    stage8(A, sA[1], m0, 1, wid, l, kch);
    stage8(Bt, sB[1], n0, 1, wid, l, kch);
    asm volatile("s_waitcnt vmcnt(8)" ::: "memory");   // K-tile 0 landed
    __builtin_amdgcn_s_barrier();
    __builtin_amdgcn_sched_barrier(0);

    for (int j = 0; j < JT; ++j) {
        const bf16* tA = sA[j & 1];
        const bf16* tB = sB[j & 1];
        bf16* wA = sA[j & 1];
        bf16* wB = sB[j & 1];

        // next-stage coordinates (tile of j+2)
        const int jn = j + 2;
        const bool doStage = jn < JT;
        int ktn = jn & (NTT - 1), m0n = 0, n0n = 0;
        if (doStage) {
            int tin = wg * T + (jn >> 4);              // NTT == 16
            m0n = (tin / NBN) << 8;
            n0n = (tin % NBN) << 8;
        }

        // ---- P1: ds aLo(8) + bLo(4); MFMA m0-1 x n0 ----
#pragma unroll
        for (int m = 0; m < 2; ++m)
#pragma unroll
            for (int ks = 0; ks < 4; ++ks)
                aLo[m][ks] = *reinterpret_cast<const bf16x8*>(&tA[(rA + m * 32) * 64 + offK[ks]]);
#pragma unroll
        for (int ks = 0; ks < 4; ++ks)
            bLo[ks] = *reinterpret_cast<const bf16x8*>(&tB[rB * 64 + offK[ks]]);
        __builtin_amdgcn_s_setprio(1);
#pragma unroll
        for (int m = 0; m < 2; ++m)
#pragma unroll
            for (int ks = 0; ks < 4; ++ks)
                acc[m][0] = __builtin_amdgcn_mfma_f32_32x32x16_bf16(aLo[m][ks], bLo[ks], acc[m][0], 0, 0, 0);
        __builtin_amdgcn_s_setprio(0);
        __builtin_amdgcn_s_barrier();
        __builtin_amdgcn_sched_barrier(0);

        // ---- P2: ds aHi(8); MFMA m2-3 x n0 ----  (A region fully read after this)
#pragma unroll
        for (int m = 0; m < 2; ++m)
#pragma unroll
            for (int ks = 0; ks < 4; ++ks)
                aHi[m][ks] = *reinterpret_cast<const bf16x8*>(&tA[(rA + 64 + m * 32) * 64 + offK[ks]]);
        __builtin_amdgcn_s_setprio(1);
#pragma unroll
        for (int m = 0; m < 2; ++m)
#pragma unroll
            for (int ks = 0; ks < 4; ++ks)
                acc[2 + m][0] = __builtin_amdgcn_mfma_f32_32x32x16_bf16(aHi[m][ks], bLo[ks], acc[2 + m][0], 0, 0, 0);
        __builtin_amdgcn_s_setprio(0);
        __builtin_amdgcn_s_barrier();
        __builtin_amdgcn_sched_barrier(0);

        // ---- P3: ds bHi(4); stage A(j+2) into freed A region; MFMA m2-3 x n1 ----
#pragma unroll
        for (int ks = 0; ks < 4; ++ks)
            bHi[ks] = *reinterpret_cast<const bf16x8*>(&tB[(rB + 32) * 64 + offK[ks]]);
        if (doStage)
            stage8(A, wA, m0n, ktn, wid, l, kch);
        __builtin_amdgcn_s_setprio(1);
#pragma unroll
        for (int m = 0; m < 2; ++m)
#pragma unroll
            for (int ks = 0; ks < 4; ++ks)
                acc[2 + m][1] = __builtin_amdgcn_mfma_f32_32x32x16_bf16(aHi[m][ks], bHi[ks], acc[2 + m][1], 0, 0, 0);
        __builtin_amdgcn_s_setprio(0);
        __builtin_amdgcn_s_barrier();
        __builtin_amdgcn_sched_barrier(0);

        // ---- P4: stage B(j+2) into freed B region; MFMA m0-1 x n1; counted vmcnt ----
        if (doStage)
            stage8(Bt, wB, n0n, ktn, wid, l, kch);
        __builtin_amdgcn_s_setprio(1);
#pragma unroll
        for (int m = 0; m < 2; ++m)
#pragma unroll
            for (int ks = 0; ks < 4; ++ks)
                acc[m][1] = __builtin_amdgcn_mfma_f32_32x32x16_bf16(aLo[m][ks], bHi[ks], acc[m][1], 0, 0, 0);
        __builtin_amdgcn_s_setprio(0);
        if (j < JT - 2)
            asm volatile("s_waitcnt vmcnt(8)" ::: "memory");   // K-tile j+1 landed
        else if (j == JT - 2)
            asm volatile("s_waitcnt vmcnt(0)" ::: "memory");   // drain for last tile
        __builtin_amdgcn_s_barrier();
        __builtin_amdgcn_sched_barrier(0);

        // ---- output-tile boundary: epilogue (no LDS access), then reset ----
        if ((j & (NTT - 1)) == NTT - 1) {
            if (OUT_MODE == 0) {
                bf16* Cb = (bf16*)Cout;
#pragma unroll
                for (int m = 0; m < 4; ++m) {
#pragma unroll
                    for (int n = 0; n < 2; ++n) {
                        int col = n0 + wn * 64 + n * 32 + l31;
#pragma unroll
                        for (int reg = 0; reg < 16; ++reg) {
                            int row = m0 + wm * 128 + m * 32 + (reg & 3) + ((reg >> 2) << 3) + (l5 << 2);
                            Cb[(size_t)row * Nn + col] = (bf16)acc[m][n][reg];
                        }
                    }
                }
            } else {
                float* Cf = (float*)Cout;
#pragma unroll
                for (int m = 0; m < 4; ++m) {
#pragma unroll
                    for (int n = 0; n < 2; ++n) {
                        int col = n0 + wn * 64 + n * 32 + l31;
                        float bv = bias[col];
#pragma unroll
                        for (int reg = 0; reg < 16; ++reg) {
                            int row = m0 + wm * 128 + m * 32 + (reg & 3) + ((reg >> 2) << 3) + (l5 << 2);
                            int lrow = row & (LL - 1);
                            float cnt = (lrow < 2 || lrow > LL - 3) ? 1.f : 2.f;
                            Cf[(size_t)row * Nn + col] = acc[m][n][reg] + bv * cnt;
                        }
                    }
                }
            }
            if (j + 1 < JT) {
#pragma unroll
                for (int m = 0; m < 4; ++m)
#pragma unroll
                    for (int n = 0; n < 2; ++n)
#pragma unroll
                        for (int reg = 0; reg < 16; ++reg)
                            acc[m][n][reg] = 0.f;
                ti += 1;
                m0 = (ti / NBN) << 8;
                n0 = (ti % NBN) << 8;
            }
        }
    }
}

// ---------------- fused windowed attention + presum: 4 waves/block ----------------
// One wave per (b, n1, h): produces the h-slice of z rows 2*n1, 2*n1+1.
// z row l = o(window n1, slot l&1) + o(window n1-1, slot (l&1)+2).
__global__ __launch_bounds__(256) void attnz_k(const bf16* __restrict__ qkv,
                                               bf16* __restrict__ z)
{
    int task = blockIdx.x * 4 + (threadIdx.x >> 6);   // (b, n1, h)
    int h = task & 7;
    int tmp = task >> 3;                              // b*1024 + n1
    int n1 = tmp & 1023;
    int b = tmp >> 10;
    int l = threadIdx.x & 63;
    const int coff = h * 128 + 2 * l;                 // this lane's 2 d-elements
    const int baserow = b * LL + 2 * n1;              // global row of q/z base
    const bool hasA = (n1 <= NW - 1);                 // window n1 exists
    const bool hasB = (n1 >= 1);                      // window n1-1 exists

    float q[2][2], k[6][2], v[6][2];
#pragma unroll
    for (int i = 0; i < 2; ++i) {
        const bf16* rp = qkv + (size_t)(baserow + i) * N3;
        u32 uq = *reinterpret_cast<const u32*>(rp + coff);
        q[i][0] = bflo(uq); q[i][1] = bfhi(uq);
    }
#pragma unroll
    for (int j = 0; j < 6; ++j) {
        int r = 2 * n1 - 2 + j;
        r = r < 0 ? 0 : (r > LL - 1 ? LL - 1 : r);    // clamp; clamped rows unused
        const bf16* rp = qkv + (size_t)(b * LL + r) * N3;
        u32 uk = *reinterpret_cast<const u32*>(rp + 1024 + coff);
        u32 uv = *reinterpret_cast<const u32*>(rp + 2048 + coff);
        k[j][0] = bflo(uk); k[j][1] = bfhi(uk);
        v[j][0] = bflo(uv); v[j][1] = bfhi(uv);
    }

    float dots[2][6];
#pragma unroll
    for (int i = 0; i < 2; ++i)
#pragma unroll
        for (int j = 0; j < 6; ++j) {
            float p = q[i][0] * k[j][0] + q[i][1] * k[j][1];
#pragma unroll
            for (int off = 32; off >= 1; off >>= 1)
                p += __shfl_xor(p, off);
            dots[i][j] = p * 0.03125f;   // * C^-0.5
        }

#pragma unroll
    for (int i = 0; i < 2; ++i) {
        float o0 = 0.f, o1 = 0.f;
        if (hasA) {    // window n1, k/v slots 2..5
            float m = fmaxf(fmaxf(dots[i][2], dots[i][3]), fmaxf(dots[i][4], dots[i][5]));
            float e[4], s = 0.f;
#pragma unroll
            for (int j = 0; j < 4; ++j) { e[j] = __expf(dots[i][2 + j] - m); s += e[j]; }
            float inv = 1.f / s;
#pragma unroll
            for (int j = 0; j < 4; ++j) {
                float a = e[j] * inv;
                o0 += a * v[2 + j][0];
                o1 += a * v[2 + j][1];
            }
        }
        if (hasB) {    // window n1-1, k/v slots 0..3
            float m = fmaxf(fmaxf(dots[i][0], dots[i][1]), fmaxf(dots[i][2], dots[i][3]));
            float e[4], s = 0.f;
#pragma unroll
            for (int j = 0; j < 4; ++j) { e[j] = __expf(dots[i][j] - m); s += e[j]; }
            float inv = 1.f / s;
#pragma unroll
            for (int j = 0; j < 4; ++j) {
                float a = e[j] * inv;
                o0 += a * v[j][0];
                o1 += a * v[j][1];
            }
        }
        u32 pk = (u32)f2bf(o0) | ((u32)f2bf(o1) << 16);
        *reinterpret_cast<u32*>(z + (size_t)(baserow + i) * CC + coff) = pk;
    }
}

// ---------------- launch ----------------
extern "C" void kernel_launch(void* const* d_in, const int* in_sizes, int n_in,
                              void* d_out, int out_size, void* d_ws, size_t ws_size,
                              hipStream_t stream)
{
    const float* x     = (const float*)d_in[0];
    const float* w_qkv = (const float*)d_in[1];
    const float* w_out = (const float*)d_in[2];
    const float* b_out = (const float*)d_in[3];
    float* out = (float*)d_out;
    char* ws = (char*)d_ws;

    // ws layout (bytes):
    bf16* xb    = (bf16*)(ws);                  // 16384*1024*2  = 33,554,432
    bf16* wqkvT = (bf16*)(ws + 33554432);       //  3072*1024*2  =  6,291,456
    bf16* woutT = (bf16*)(ws + 39845888);       //  1024*1024*2  =  2,097,152
    bf16* qkvb  = (bf16*)(ws + 41943040);       // 16384*3072*2  = 100,663,296 (ends 142,606,336)
    bf16* z     = (bf16*)(ws + 142606336);      // 16384*1024*2  = 33,554,432
    // total: 176,160,768 bytes

    cast_x_k<<<2048, 256, 0, stream>>>(x, xb, M1 * CC / 4);
    transpose_cast_k<<<dim3(N3 / 32, CC / 32), 256, 0, stream>>>(w_qkv, wqkvT, CC, N3);
    transpose_cast_k<<<dim3(CC / 32, CC / 32), 256, 0, stream>>>(w_out, woutT, CC, CC);

    // GEMM1: 16384x3072x1024 = 768 tiles -> 256 persistent blocks x 3 tiles
    gemm8p_k<0, 3, 12><<<256, 512, 0, stream>>>(xb, wqkvT, qkvb, nullptr);

    // fused attention + presum: tasks = B*1024*H = 65536, 4 waves/block
    attnz_k<<<BB * 1024 * HEADS / 4, 256, 0, stream>>>(qkvb, z);

    // GEMM2: 16384x1024x1024 = 256 tiles -> 256 blocks x 1 tile, f32 out + bias*cnt
    gemm8p_k<1, 1, 4><<<256, 512, 0, stream>>>(z, woutT, out, b_out);
}

// Round 12
// 227.188 us; speedup vs baseline: 1.1231x; 1.1231x over previous
//
#include <hip/hip_runtime.h>
#include <stdint.h>

// ---- problem constants ----
#define HEADS 8
#define KSZ   4
#define STRD  2
#define BB    8
#define LL    2048
#define CC    1024
#define N3    3072
#define NW    1023            // windows
#define M1    (BB*LL)         // 16384 rows of qkv GEMM (and of z GEMM)
#define GK    1024            // K of both GEMMs
#define NTT   16              // K-tiles per output tile (GK/64)

typedef __bf16 bf16;
typedef __bf16 bf16x8 __attribute__((ext_vector_type(8)));
typedef float  f32x4  __attribute__((ext_vector_type(4)));
typedef unsigned int  u32;
typedef unsigned short u16;

__device__ __forceinline__ float bflo(u32 u) { return __uint_as_float(u << 16); }
__device__ __forceinline__ float bfhi(u32 u) { return __uint_as_float(u & 0xffff0000u); }
__device__ __forceinline__ u16 f2bf(float f) { bf16 b = (bf16)f; return __builtin_bit_cast(u16, b); }

#define AS3(p) ((__attribute__((address_space(3))) void*)(p))
#define AS1(p) ((const __attribute__((address_space(1))) void*)(p))

// ---------------- merged prep: cast x + transpose both weights ----------------
// blocks [0,2048): cast x -> xb (grid-stride float4)
// blocks [2048,5120): transpose w_qkv (1024x3072) -> wqkvT (3072x1024)
// blocks [5120,6144): transpose w_out (1024x1024) -> woutT
__device__ __forceinline__ void tr_block(const float* __restrict__ src,
                                         bf16* __restrict__ dst,
                                         int R, int Ccol, int c0, int r0)
{
    __shared__ float t[32][33];
    int tx = threadIdx.x & 31, ty = threadIdx.x >> 5;   // 32 x 8
#pragma unroll
    for (int yy = 0; yy < 32; yy += 8)
        t[ty + yy][tx] = src[(size_t)(r0 + ty + yy) * Ccol + c0 + tx];
    __syncthreads();
#pragma unroll
    for (int yy = 0; yy < 32; yy += 8)
        dst[(size_t)(c0 + ty + yy) * R + r0 + tx] = (bf16)t[tx][ty + yy];
}

__global__ __launch_bounds__(256) void prep_k(const float* __restrict__ x,
                                              bf16* __restrict__ xb,
                                              const float* __restrict__ w_qkv,
                                              bf16* __restrict__ wqkvT,
                                              const float* __restrict__ w_out,
                                              bf16* __restrict__ woutT)
{
    int bid = blockIdx.x;
    if (bid < 2048) {
        const int n4 = M1 * CC / 4;
        int i = bid * 256 + threadIdx.x;
        for (; i < n4; i += 2048 * 256) {
            float4 f = reinterpret_cast<const float4*>(x)[i];
            ushort4 u;
            u.x = f2bf(f.x); u.y = f2bf(f.y); u.z = f2bf(f.z); u.w = f2bf(f.w);
            reinterpret_cast<ushort4*>(xb)[i] = u;
        }
    } else if (bid < 5120) {
        int t = bid - 2048;                 // 3072 blocks: 96 x 32
        tr_block(w_qkv, wqkvT, CC, N3, (t % 96) * 32, (t / 96) * 32);
    } else {
        int t = bid - 5120;                 // 1024 blocks: 32 x 32
        tr_block(w_out, woutT, CC, CC, (t & 31) * 32, (t >> 5) * 32);
    }
}

// ---------------- persistent 256x256 8-phase bf16 GEMM (r8 verified body) ----------------
// Rolled j-loop, reads after leading barrier, stage A(j+2)@P3, B(j+2)@P4 into
// buf[j&1]; vmcnt(8)@P4 steady, vmcnt(0)@JT-2. NBN template (magic-mul div).
// OUT_MODE 0 = bf16 C, 1 = f32 C direct to d_out with bias[col]*cnt(row).
__device__ __forceinline__ void stage8(const bf16* __restrict__ G, bf16* dst,
                                       int baserow, int kt,
                                       int wid, int l, int kch)
{
#pragma unroll
    for (int qd = 0; qd < 4; ++qd) {
        int row = ((wid * 4 + qd) << 3) + (l >> 3);
        const bf16* src = G + (size_t)(baserow + row) * GK + kt * 64 + kch;
        __builtin_amdgcn_global_load_lds(AS1(src), AS3(dst + (wid * 4 + qd) * 512), 16, 0, 0);
    }
}

template <int OUT_MODE, int T, int NBN>
__global__ __launch_bounds__(512, 1) void gemm8p_k(const bf16* __restrict__ A,
                                                   const bf16* __restrict__ Bt,
                                                   void* __restrict__ Cout,
                                                   const float* __restrict__ bias)
{
    __shared__ __attribute__((aligned(16))) bf16 sA[2][256 * 64];
    __shared__ __attribute__((aligned(16))) bf16 sB[2][256 * 64];
    const int Nn = NBN << 8;

    const int tid = threadIdx.x;
    const int l = tid & 63, wid = tid >> 6;
    const int wm = wid >> 2, wn = wid & 3;
    const int l15 = l & 15, l4 = l >> 4;
    const int xr = (l & 7) << 4;                      // read-side byte XOR (row&7 == l&7)
    const int kch = ((l & 7) ^ ((l >> 3) & 7)) * 8;   // write-side inverse-swizzled k offset

    // XCD-aware block swizzle (grid = 256, % 8 == 0, bijective)
    const int nwg = gridDim.x;
    const int wg = ((blockIdx.x & 7) * (nwg >> 3)) + (blockIdx.x >> 3);
    const int JT = T * NTT;

    int ti = wg * T;                                  // current output tile
    int m0 = (ti / NBN) << 8, n0 = (ti % NBN) << 8;

    const int rA = wm * 128 + l15;
    const int rB = wn * 64 + l15;
    int offK[2];
#pragma unroll
    for (int ks = 0; ks < 2; ++ks)
        offK[ks] = ((ks * 64 + l4 * 16) ^ xr) >> 1;

    f32x4 acc[8][4] = {};
    bf16x8 aLo[4][2], aHi[4][2], bLo[2][2], bHi[2][2];

    // prologue: K-tile 0 -> buf0, K-tile 1 -> buf1 (tile ti)
    stage8(A, sA[0], m0, 0, wid, l, kch);
    stage8(Bt, sB[0], n0, 0, wid, l, kch);
    stage8(A, sA[1], m0, 1, wid, l, kch);
    stage8(Bt, sB[1], n0, 1, wid, l, kch);
    asm volatile("s_waitcnt vmcnt(8)" ::: "memory");   // K-tile 0 landed
    __builtin_amdgcn_s_barrier();
    __builtin_amdgcn_sched_barrier(0);

    for (int j = 0; j < JT; ++j) {
        const bf16* tA = sA[j & 1];
        const bf16* tB = sB[j & 1];
        bf16* wA = sA[j & 1];
        bf16* wB = sB[j & 1];

        // next-stage coordinates (tile of j+2)
        const int jn = j + 2;
        const bool doStage = jn < JT;
        int ktn = jn & (NTT - 1), m0n = 0, n0n = 0;
        if (doStage) {
            int tin = wg * T + (jn >> 4);              // NTT == 16
            m0n = (tin / NBN) << 8;
            n0n = (tin % NBN) << 8;
        }

        // ---- P1: ds aLo(8) + bLo(4); MFMA m0-3 x n0-1 ----
#pragma unroll
        for (int m = 0; m < 4; ++m)
#pragma unroll
            for (int ks = 0; ks < 2; ++ks)
                aLo[m][ks] = *reinterpret_cast<const bf16x8*>(&tA[(rA + m * 16) * 64 + offK[ks]]);
#pragma unroll
        for (int n = 0; n < 2; ++n)
#pragma unroll
            for (int ks = 0; ks < 2; ++ks)
                bLo[n][ks] = *reinterpret_cast<const bf16x8*>(&tB[(rB + n * 16) * 64 + offK[ks]]);
        __builtin_amdgcn_s_setprio(1);
#pragma unroll
        for (int m = 0; m < 4; ++m)
#pragma unroll
            for (int n = 0; n < 2; ++n)
#pragma unroll
                for (int ks = 0; ks < 2; ++ks)
                    acc[m][n] = __builtin_amdgcn_mfma_f32_16x16x32_bf16(aLo[m][ks], bLo[n][ks], acc[m][n], 0, 0, 0);
        __builtin_amdgcn_s_setprio(0);
        __builtin_amdgcn_s_barrier();
        __builtin_amdgcn_sched_barrier(0);

        // ---- P2: ds aHi(8); MFMA m4-7 x n0-1 ----  (A region fully read after this)
#pragma unroll
        for (int m = 0; m < 4; ++m)
#pragma unroll
            for (int ks = 0; ks < 2; ++ks)
                aHi[m][ks] = *reinterpret_cast<const bf16x8*>(&tA[(rA + 64 + m * 16) * 64 + offK[ks]]);
        __builtin_amdgcn_s_setprio(1);
#pragma unroll
        for (int m = 0; m < 4; ++m)
#pragma unroll
            for (int n = 0; n < 2; ++n)
#pragma unroll
                for (int ks = 0; ks < 2; ++ks)
                    acc[4 + m][n] = __builtin_amdgcn_mfma_f32_16x16x32_bf16(aHi[m][ks], bLo[n][ks], acc[4 + m][n], 0, 0, 0);
        __builtin_amdgcn_s_setprio(0);
        __builtin_amdgcn_s_barrier();
        __builtin_amdgcn_sched_barrier(0);

        // ---- P3: ds bHi(4); stage A(j+2) into freed A region; MFMA m4-7 x n2-3 ----
#pragma unroll
        for (int n = 0; n < 2; ++n)
#pragma unroll
            for (int ks = 0; ks < 2; ++ks)
                bHi[n][ks] = *reinterpret_cast<const bf16x8*>(&tB[(rB + 32 + n * 16) * 64 + offK[ks]]);
        if (doStage)
            stage8(A, wA, m0n, ktn, wid, l, kch);
        __builtin_amdgcn_s_setprio(1);
#pragma unroll
        for (int m = 0; m < 4; ++m)
#pragma unroll
            for (int n = 0; n < 2; ++n)
#pragma unroll
                for (int ks = 0; ks < 2; ++ks)
                    acc[4 + m][2 + n] = __builtin_amdgcn_mfma_f32_16x16x32_bf16(aHi[m][ks], bHi[n][ks], acc[4 + m][2 + n], 0, 0, 0);
        __builtin_amdgcn_s_setprio(0);
        __builtin_amdgcn_s_barrier();
        __builtin_amdgcn_sched_barrier(0);

        // ---- P4: stage B(j+2) into freed B region; MFMA m0-3 x n2-3; counted vmcnt ----
        if (doStage)
            stage8(Bt, wB, n0n, ktn, wid, l, kch);
        __builtin_amdgcn_s_setprio(1);
#pragma unroll
        for (int m = 0; m < 4; ++m)
#pragma unroll
            for (int n = 0; n < 2; ++n)
#pragma unroll
                for (int ks = 0; ks < 2; ++ks)
                    acc[m][2 + n] = __builtin_amdgcn_mfma_f32_16x16x32_bf16(aLo[m][ks], bHi[n][ks], acc[m][2 + n], 0, 0, 0);
        __builtin_amdgcn_s_setprio(0);
        if (j < JT - 2)
            asm volatile("s_waitcnt vmcnt(8)" ::: "memory");   // K-tile j+1 landed
        else if (j == JT - 2)
            asm volatile("s_waitcnt vmcnt(0)" ::: "memory");   // drain for last tile
        __builtin_amdgcn_s_barrier();
        __builtin_amdgcn_sched_barrier(0);

        // ---- output-tile boundary: epilogue (no LDS access), then reset ----
        if ((j & (NTT - 1)) == NTT - 1) {
            if (OUT_MODE == 0) {
                bf16* Cb = (bf16*)Cout;
#pragma unroll
                for (int m = 0; m < 8; ++m) {
                    int row = m0 + wm * 128 + m * 16 + l4 * 4;
#pragma unroll
                    for (int n = 0; n < 4; ++n) {
                        int col = n0 + wn * 64 + n * 16 + l15;
#pragma unroll
                        for (int r = 0; r < 4; ++r)
                            Cb[(size_t)(row + r) * Nn + col] = (bf16)acc[m][n][r];
                    }
                }
            } else {
                float* Cf = (float*)Cout;
#pragma unroll
                for (int m = 0; m < 8; ++m) {
                    int row = m0 + wm * 128 + m * 16 + l4 * 4;
#pragma unroll
                    for (int n = 0; n < 4; ++n) {
                        int col = n0 + wn * 64 + n * 16 + l15;
                        float bv = bias[col];
#pragma unroll
                        for (int r = 0; r < 4; ++r) {
                            int lrow = (row + r) & (LL - 1);
                            float cnt = (lrow < 2 || lrow > LL - 3) ? 1.f : 2.f;
                            Cf[(size_t)(row + r) * Nn + col] = acc[m][n][r] + bv * cnt;
                        }
                    }
                }
            }
            if (j + 1 < JT) {
#pragma unroll
                for (int m = 0; m < 8; ++m)
#pragma unroll
                    for (int n = 0; n < 4; ++n)
#pragma unroll
                        for (int r = 0; r < 4; ++r)
                            acc[m][n][r] = 0.f;
                ti += 1;
                m0 = (ti / NBN) << 8;
                n0 = (ti % NBN) << 8;
            }
        }
    }
}

// ---------------- fused attention + presum, paired windows: 4 waves/block ----------------
// One wave per (b, p, h), p in [0,512): handles windows n1=2p and n1'=2p+1,
// producing the h-slice of z rows 4p..4p+3. K/V union = 8 rows (slots s=0..7
// <-> row 4p-2+s), cutting K/V re-reads from 3x to 2x.
// z row 4p+i: contribution "Lo" = softmaxPV over j=0..3 (v slot base+j),
//             contribution "Hi" = softmaxPV over j=2..5; base = (i<2)?0:2.
// cLo: i<2 -> p>0 (window 2p-1), i>=2 -> always (window 2p).
// cHi: i<2 -> always (window 2p), i>=2 -> p<511 (window 2p+1).
__global__ __launch_bounds__(256) void attnz2_k(const bf16* __restrict__ qkv,
                                                bf16* __restrict__ z)
{
    // XCD-chunked swizzle over 8192 blocks: contiguous (b,p) range per XCD
    int bid = (blockIdx.x & 7) * 1024 + (blockIdx.x >> 3);
    int task = bid * 4 + (threadIdx.x >> 6);   // (b, p, h), h fastest
    int h = task & 7;
    int tmp = task >> 3;                       // b*512 + p
    int p = tmp & 511;
    int b = tmp >> 9;
    int l = threadIdx.x & 63;
    const int coff = h * 128 + 2 * l;          // this lane's 2 d-elements
    const int browz = b * LL + 4 * p;          // z base row (4 rows)

    float q[4][2], k[8][2], v[8][2];
#pragma unroll
    for (int i = 0; i < 4; ++i) {
        const bf16* rp = qkv + (size_t)(browz + i) * N3;
        u32 uq = *reinterpret_cast<const u32*>(rp + coff);
        q[i][0] = bflo(uq); q[i][1] = bfhi(uq);
    }
#pragma unroll
    for (int s = 0; s < 8; ++s) {
        int r = 4 * p - 2 + s;
        r = r < 0 ? 0 : (r > LL - 1 ? LL - 1 : r);    // clamp; clamped rows unused
        const bf16* rp = qkv + (size_t)(b * LL + r) * N3;
        u32 uk = *reinterpret_cast<const u32*>(rp + 1024 + coff);
        u32 uv = *reinterpret_cast<const u32*>(rp + 2048 + coff);
        k[s][0] = bflo(uk); k[s][1] = bfhi(uk);
        v[s][0] = bflo(uv); v[s][1] = bfhi(uv);
    }

    // dots[i][j] = q_i . k[base_i + j], j in 0..5, base_i = (i<2)?0:2
    float dots[4][6];
#pragma unroll
    for (int i = 0; i < 4; ++i) {
        const int base = (i < 2) ? 0 : 2;
#pragma unroll
        for (int j = 0; j < 6; ++j) {
            float pp = q[i][0] * k[base + j][0] + q[i][1] * k[base + j][1];
#pragma unroll
            for (int off = 32; off >= 1; off >>= 1)
                pp += __shfl_xor(pp, off);
            dots[i][j] = pp * 0.03125f;   // * C^-0.5
        }
    }

#pragma unroll
    for (int i = 0; i < 4; ++i) {
        const int base = (i < 2) ? 0 : 2;
        const bool cLo = (i < 2) ? (p > 0) : true;
        const bool cHi = (i < 2) ? true : (p < 511);
        float o0 = 0.f, o1 = 0.f;
        if (cLo) {    // window over j 0..3
            float m = fmaxf(fmaxf(dots[i][0], dots[i][1]), fmaxf(dots[i][2], dots[i][3]));
            float e[4], s = 0.f;
#pragma unroll
            for (int j = 0; j < 4; ++j) { e[j] = __expf(dots[i][j] - m); s += e[j]; }
            float inv = 1.f / s;
#pragma unroll
            for (int j = 0; j < 4; ++j) {
                float a = e[j] * inv;
                o0 += a * v[base + j][0];
                o1 += a * v[base + j][1];
            }
        }
        if (cHi) {    // window over j 2..5
            float m = fmaxf(fmaxf(dots[i][2], dots[i][3]), fmaxf(dots[i][4], dots[i][5]));
            float e[4], s = 0.f;
#pragma unroll
            for (int j = 0; j < 4; ++j) { e[j] = __expf(dots[i][2 + j] - m); s += e[j]; }
            float inv = 1.f / s;
#pragma unroll
            for (int j = 0; j < 4; ++j) {
                float a = e[j] * inv;
                o0 += a * v[base + 2 + j][0];
                o1 += a * v[base + 2 + j][1];
            }
        }
        u32 pk = (u32)f2bf(o0) | ((u32)f2bf(o1) << 16);
        *reinterpret_cast<u32*>(z + (size_t)(browz + i) * CC + coff) = pk;
    }
}

// ---------------- launch ----------------
extern "C" void kernel_launch(void* const* d_in, const int* in_sizes, int n_in,
                              void* d_out, int out_size, void* d_ws, size_t ws_size,
                              hipStream_t stream)
{
    const float* x     = (const float*)d_in[0];
    const float* w_qkv = (const float*)d_in[1];
    const float* w_out = (const float*)d_in[2];
    const float* b_out = (const float*)d_in[3];
    float* out = (float*)d_out;
    char* ws = (char*)d_ws;

    // ws layout (bytes):
    bf16* xb    = (bf16*)(ws);                  // 16384*1024*2  = 33,554,432
    bf16* wqkvT = (bf16*)(ws + 33554432);       //  3072*1024*2  =  6,291,456
    bf16* woutT = (bf16*)(ws + 39845888);       //  1024*1024*2  =  2,097,152
    bf16* qkvb  = (bf16*)(ws + 41943040);       // 16384*3072*2  = 100,663,296 (ends 142,606,336)
    bf16* z     = (bf16*)(ws + 142606336);      // 16384*1024*2  = 33,554,432
    // total: 176,160,768 bytes

    // merged prep: cast x + transpose w_qkv + transpose w_out
    prep_k<<<6144, 256, 0, stream>>>(x, xb, w_qkv, wqkvT, w_out, woutT);

    // GEMM1: 16384x3072x1024 = 768 tiles -> 256 persistent blocks x 3 tiles
    gemm8p_k<0, 3, 12><<<256, 512, 0, stream>>>(xb, wqkvT, qkvb, nullptr);

    // fused attention + presum (paired windows): 8*512*8 = 32768 waves, 4/block
    attnz2_k<<<8192, 256, 0, stream>>>(qkvb, z);

    // GEMM2: 16384x1024x1024 = 256 tiles -> 256 blocks x 1 tile, f32 out + bias*cnt
    gemm8p_k<1, 1, 4><<<256, 512, 0, stream>>>(z, woutT, out, b_out);
}